// Round 3
// baseline (519.763 us; speedup 1.0000x reference)
//
#include <hip/hip_runtime.h>
#include <cstdint>

#define B_ 16384
#define S_ 1024
#define L_ 256
#define K_ 4096
#define H_ 64
#define TAU 0.006f

typedef __attribute__((ext_vector_type(8))) short short8;
typedef __attribute__((ext_vector_type(4))) float floatx4;

#define AS1 __attribute__((address_space(1)))
#define AS3 __attribute__((address_space(3)))

__device__ __forceinline__ unsigned int f2ord(float f) {
  unsigned int u = __float_as_uint(f);
  return (u & 0x80000000u) ? ~u : (u | 0x80000000u);
}
__device__ __forceinline__ float ord2f(unsigned int o) {
  unsigned int u = (o & 0x80000000u) ? (o ^ 0x80000000u) : ~o;
  return __uint_as_float(u);
}
// round-to-nearest-even fp32 -> bf16
__device__ __forceinline__ unsigned short bf16rne(float f, float* hif) {
  unsigned int u = __float_as_uint(f);
  unsigned int r = (u + 0x7fffu + ((u >> 16) & 1u)) >> 16;
  *hif = __uint_as_float(r << 16);
  return (unsigned short)r;
}
__device__ __forceinline__ void bf16split(float f, unsigned short* hi, unsigned short* lo) {
  float hif, d;
  *hi = bf16rne(f, &hif);
  *lo = bf16rne(f - hif, &d);
}

__device__ __forceinline__ void fma16(const float a[4], const float b[4], float acc[4][4]) {
#pragma unroll
  for (int ii = 0; ii < 4; ++ii)
#pragma unroll
    for (int jj = 0; jj < 4; ++jj)
      acc[ii][jj] = fmaf(a[ii], b[jj], acc[ii][jj]);
}

// ---------------- K0a: wnorm[c] = ||emb[c]||^2 ----------------
__global__ __launch_bounds__(256)
void wnorm_kernel(const float* __restrict__ emb, float* __restrict__ wnorm) {
  const int lane = threadIdx.x & 63, wv = threadIdx.x >> 6;
  const int c = blockIdx.x * 4 + wv;
  const float4 v = *(const float4*)(emb + (long)c * L_ + (lane << 2));
  float s = v.x * v.x + v.y * v.y + v.z * v.z + v.w * v.w;
#pragma unroll
  for (int off = 32; off > 0; off >>= 1) s += __shfl_down(s, off, 64);
  if (lane == 0) wnorm[c] = s;
}

// ---------------- K0b: emb -> bf16 hi/lo ----------------
__global__ __launch_bounds__(256)
void cvt_emb_kernel(const float* __restrict__ emb, unsigned short* __restrict__ hi,
                    unsigned short* __restrict__ lo) {
  const size_t i = ((size_t)blockIdx.x * 256 + threadIdx.x) * 4;
  const float4 v = *(const float4*)(emb + i);
  ushort4 hv, lv;
  bf16split(v.x, &hv.x, &lv.x);
  bf16split(v.y, &hv.y, &lv.y);
  bf16split(v.z, &hv.z, &lv.z);
  bf16split(v.w, &hv.w, &lv.w);
  *(ushort4*)(hi + i) = hv;
  *(ushort4*)(lo + i) = lv;
}

// ---------------- K0c: transpose+split: dst[c][r] = src[r][c] (hi/lo bf16) ----------------
// grid (scols/64, srows/64)
__global__ __launch_bounds__(256)
void tsplit_kernel(const float* __restrict__ src, int srows, int scols,
                   unsigned short* __restrict__ hi, unsigned short* __restrict__ lo) {
  __shared__ float tile[64][68];
  const int t = threadIdx.x;
  const int r0 = blockIdx.y * 64, c0 = blockIdx.x * 64;
  const int a = t & 63, q = t >> 6;
#pragma unroll
  for (int i = 0; i < 4; ++i) {
    const int cq = q * 16 + i * 4;
    *(float4*)&tile[a][cq] = *(const float4*)(src + (size_t)(r0 + a) * scols + c0 + cq);
  }
  __syncthreads();
  const int rx = t & 15, cy = t >> 4;
#pragma unroll
  for (int i = 0; i < 4; ++i) {
    const int cl = i * 16 + cy;
    float4 w;
    w.x = tile[rx * 4 + 0][cl];
    w.y = tile[rx * 4 + 1][cl];
    w.z = tile[rx * 4 + 2][cl];
    w.w = tile[rx * 4 + 3][cl];
    ushort4 hv, lv;
    bf16split(w.x, &hv.x, &lv.x);
    bf16split(w.y, &hv.y, &lv.y);
    bf16split(w.z, &hv.z, &lv.z);
    bf16split(w.w, &hv.w, &lv.w);
    *(ushort4*)(hi + (size_t)(c0 + cl) * srows + r0 + rx * 4) = hv;
    *(ushort4*)(lo + (size_t)(c0 + cl) * srows + r0 + rx * 4) = lv;
  }
}

// ---------------- K1: h = relu(x @ w1 + b1), [k][r] LDS (conflict-free reads) ----------------
__global__ __launch_bounds__(256)
void enc1_kernel(const float* __restrict__ x, const float* __restrict__ w1,
                 const float* __restrict__ b1, float* __restrict__ h) {
  __shared__ float xs[64][68];   // [k][r], pad 68: b128 reads 2-way
  __shared__ float ws[64][64];   // [k][c]
  const int t = threadIdx.x;
  const int tx = t & 15, ty = t >> 4;
  const long row0 = (long)blockIdx.x * 64;
  float acc[4][4] = {};
  for (int k0 = 0; k0 < S_; k0 += 64) {
#pragma unroll
    for (int i = 0; i < 4; ++i) {
      const int r = ty + 16 * i;
      const float4 v = *(const float4*)(x + (row0 + r) * S_ + k0 + (tx << 2));
      xs[4 * tx + 0][r] = v.x;
      xs[4 * tx + 1][r] = v.y;
      xs[4 * tx + 2][r] = v.z;
      xs[4 * tx + 3][r] = v.w;
    }
#pragma unroll
    for (int i = 0; i < 4; ++i) {
      const int g = (i << 8) + t;
      const int kk = g >> 4, c = (g & 15) << 2;
      *(float4*)&ws[kk][c] = *(const float4*)(w1 + (long)(k0 + kk) * H_ + c);
    }
    __syncthreads();
#pragma unroll 4
    for (int k = 0; k < 64; ++k) {
      float a[4], b[4];
      const float4 av = *(const float4*)&xs[k][ty << 2];
      a[0] = av.x; a[1] = av.y; a[2] = av.z; a[3] = av.w;
      const float4 bv = *(const float4*)&ws[k][tx << 2];
      b[0] = bv.x; b[1] = bv.y; b[2] = bv.z; b[3] = bv.w;
      fma16(a, b, acc);
    }
    __syncthreads();
  }
  const float4 bb = *(const float4*)(b1 + (tx << 2));
  const float bbv[4] = {bb.x, bb.y, bb.z, bb.w};
#pragma unroll
  for (int ii = 0; ii < 4; ++ii) {
    float4 o;
    o.x = fmaxf(acc[ii][0] + bbv[0], 0.f);
    o.y = fmaxf(acc[ii][1] + bbv[1], 0.f);
    o.z = fmaxf(acc[ii][2] + bbv[2], 0.f);
    o.w = fmaxf(acc[ii][3] + bbv[3], 0.f);
    *(float4*)(h + (row0 + (ty << 2) + ii) * S_ * 0 + (row0 + (ty << 2) + ii) * H_ + (tx << 2)) = o;
  }
}

// ---------------- K2: e = h @ w2 + b2 (fp32 + bf16 hi/lo), [k][r] LDS ----------------
__global__ __launch_bounds__(256)
void enc2_kernel(const float* __restrict__ h, const float* __restrict__ w2,
                 const float* __restrict__ b2, float* __restrict__ e32,
                 unsigned short* __restrict__ e_hi, unsigned short* __restrict__ e_lo) {
  __shared__ float hs[64][68];   // [k][r]
  __shared__ float ws[64][64];   // [k][c]
  const int t = threadIdx.x;
  const int tx = t & 15, ty = t >> 4;
  const long row0 = (long)blockIdx.x * 64;
#pragma unroll
  for (int i = 0; i < 4; ++i) {
    const int r = ty + 16 * i;
    const float4 v = *(const float4*)(h + (row0 + r) * H_ + (tx << 2));
    hs[4 * tx + 0][r] = v.x;
    hs[4 * tx + 1][r] = v.y;
    hs[4 * tx + 2][r] = v.z;
    hs[4 * tx + 3][r] = v.w;
  }
  for (int c0 = 0; c0 < L_; c0 += 64) {
#pragma unroll
    for (int i = 0; i < 4; ++i) {
      const int g = (i << 8) + t;
      const int kk = g >> 4, c = (g & 15) << 2;
      *(float4*)&ws[kk][c] = *(const float4*)(w2 + (long)kk * L_ + c0 + c);
    }
    __syncthreads();
    float acc[4][4] = {};
#pragma unroll 4
    for (int k = 0; k < 64; ++k) {
      float a[4], b[4];
      const float4 av = *(const float4*)&hs[k][ty << 2];
      a[0] = av.x; a[1] = av.y; a[2] = av.z; a[3] = av.w;
      const float4 bv = *(const float4*)&ws[k][tx << 2];
      b[0] = bv.x; b[1] = bv.y; b[2] = bv.z; b[3] = bv.w;
      fma16(a, b, acc);
    }
    const float4 bb = *(const float4*)(b2 + c0 + (tx << 2));
#pragma unroll
    for (int ii = 0; ii < 4; ++ii) {
      const long row = row0 + (ty << 2) + ii;
      float4 o;
      o.x = acc[ii][0] + bb.x;
      o.y = acc[ii][1] + bb.y;
      o.z = acc[ii][2] + bb.z;
      o.w = acc[ii][3] + bb.w;
      *(float4*)(e32 + row * L_ + c0 + (tx << 2)) = o;
      ushort4 hv, lv;
      bf16split(o.x, &hv.x, &lv.x);
      bf16split(o.y, &hv.y, &lv.y);
      bf16split(o.z, &hv.z, &lv.z);
      bf16split(o.w, &hv.w, &lv.w);
      *(ushort4*)(e_hi + row * L_ + c0 + (tx << 2)) = hv;
      *(ushort4*)(e_lo + row * L_ + c0 + (tx << 2)) = lv;
    }
    __syncthreads();
  }
}

// ---------------- K3: MFMA split-bf16 distance + per-row top-2 (unchanged) ----------------
__global__ __launch_bounds__(256)
void distb_kernel(const unsigned short* __restrict__ emb_hi, const unsigned short* __restrict__ emb_lo,
                  const unsigned short* __restrict__ e_hi, const unsigned short* __restrict__ e_lo,
                  const float* __restrict__ wnorm, unsigned long long* __restrict__ part) {
  __shared__ char smem[4 * 8192];
  __shared__ float wnorm_s[128];
  const int t = threadIdx.x;
  const int lane = t & 63, wv = t >> 6;
  const int wm = wv >> 1, wn = wv & 1;
  const int n0 = blockIdx.x * 128;

  const int lr = lane >> 2;
  const int sst = (lr + (lane >> 4)) & 3;
  const int qsrc = ((lane & 3) - sst) & 3;
  const size_t lane_goff = (size_t)lr * (L_ * 2) + (size_t)qsrc * 16;

  const int ln = lane & 15, quad = lane >> 4;
  const int sfr = (ln + (ln >> 2)) & 3;
  const int qp = (quad + sfr) & 3;

  char* const sAhi = smem;
  char* const sAlo = smem + 8192;
  char* const sBhi = smem + 16384;
  char* const sBlo = smem + 24576;
  char* const myTile = smem + wv * 8192;

  unsigned long long b1[4] = {~0ull, ~0ull, ~0ull, ~0ull};
  unsigned long long b2[4] = {~0ull, ~0ull, ~0ull, ~0ull};

  for (int mt = 0; mt < 4; ++mt) {
    const int m0 = (blockIdx.y * 4 + mt) * 128;
    const char* gbase;
    if (wv == 0)      gbase = (const char*)emb_hi + (size_t)m0 * L_ * 2;
    else if (wv == 1) gbase = (const char*)emb_lo + (size_t)m0 * L_ * 2;
    else if (wv == 2) gbase = (const char*)e_hi + (size_t)n0 * L_ * 2;
    else              gbase = (const char*)e_lo + (size_t)n0 * L_ * 2;

    floatx4 acc[4][4];
#pragma unroll
    for (int a = 0; a < 4; ++a)
#pragma unroll
      for (int b = 0; b < 4; ++b) acc[a][b] = (floatx4){0.f, 0.f, 0.f, 0.f};

    for (int kc = 0; kc < 8; ++kc) {
      const char* gsrc = gbase + (size_t)(kc * 64) + lane_goff;
#pragma unroll
      for (int j = 0; j < 8; ++j) {
        __builtin_amdgcn_global_load_lds((const AS1 void*)(gsrc + (size_t)j * (16 * L_ * 2)),
                                         (AS3 void*)(myTile + j * 1024), 16, 0, 0);
      }
      __syncthreads();
      short8 ahi[4], alo[4], bhi[4], blo[4];
#pragma unroll
      for (int mf = 0; mf < 4; ++mf) {
        const int rb = (wm * 64 + mf * 16 + ln) * 64 + qp * 16;
        ahi[mf] = *(const short8*)(sAhi + rb);
        alo[mf] = *(const short8*)(sAlo + rb);
      }
#pragma unroll
      for (int nf = 0; nf < 4; ++nf) {
        const int rb = (wn * 64 + nf * 16 + ln) * 64 + qp * 16;
        bhi[nf] = *(const short8*)(sBhi + rb);
        blo[nf] = *(const short8*)(sBlo + rb);
      }
#pragma unroll
      for (int mf = 0; mf < 4; ++mf)
#pragma unroll
        for (int nf = 0; nf < 4; ++nf) {
          acc[mf][nf] = __builtin_amdgcn_mfma_f32_16x16x32_bf16(ahi[mf], bhi[nf], acc[mf][nf], 0, 0, 0);
          acc[mf][nf] = __builtin_amdgcn_mfma_f32_16x16x32_bf16(ahi[mf], blo[nf], acc[mf][nf], 0, 0, 0);
          acc[mf][nf] = __builtin_amdgcn_mfma_f32_16x16x32_bf16(alo[mf], bhi[nf], acc[mf][nf], 0, 0, 0);
        }
      __syncthreads();
    }
    if (t < 128) wnorm_s[t] = wnorm[m0 + t];
    __syncthreads();
#pragma unroll
    for (int nf = 0; nf < 4; ++nf) {
#pragma unroll
      for (int mf = 0; mf < 4; ++mf) {
#pragma unroll
        for (int rr = 0; rr < 4; ++rr) {
          const int ml = wm * 64 + mf * 16 + quad * 4 + rr;
          const float score = fmaf(-2.f, acc[mf][nf][rr], wnorm_s[ml]);
          const unsigned long long key =
              ((unsigned long long)f2ord(score) << 32) | (unsigned int)(m0 + ml);
          if (key < b1[nf]) { b2[nf] = b1[nf]; b1[nf] = key; }
          else if (key < b2[nf]) b2[nf] = key;
        }
      }
    }
    __syncthreads();
  }
#pragma unroll
  for (int d = 16; d <= 32; d <<= 1) {
#pragma unroll
    for (int nf = 0; nf < 4; ++nf) {
      const unsigned long long o1 = __shfl_xor(b1[nf], d, 64);
      const unsigned long long o2 = __shfl_xor(b2[nf], d, 64);
      const unsigned long long n1 = o1 < b1[nf] ? o1 : b1[nf];
      const unsigned long long hm = o1 < b1[nf] ? b1[nf] : o1;
      const unsigned long long l2 = o2 < b2[nf] ? o2 : b2[nf];
      b1[nf] = n1;
      b2[nf] = hm < l2 ? hm : l2;
    }
  }
  if (lane < 16) {
    const int slice = blockIdx.y * 2 + wm;
#pragma unroll
    for (int nf = 0; nf < 4; ++nf) {
      const int row = n0 + wn * 64 + nf * 16 + lane;
      const size_t slot = ((size_t)slice * B_ + row) * 2;
      part[slot] = b1[nf];
      part[slot + 1] = b2[nf];
    }
  }
}

// ---------------- K4: merge partials, flag small-gap rows ----------------
__global__ __launch_bounds__(256)
void finalize_kernel(const unsigned long long* __restrict__ part, int* __restrict__ idx,
                     int* __restrict__ flagged, int* __restrict__ counter) {
  const int row = blockIdx.x * 256 + threadIdx.x;
  unsigned long long b1 = ~0ull, b2 = ~0ull;
#pragma unroll
  for (int s = 0; s < 16; ++s) {
    const unsigned long long o1 = part[((size_t)s * B_ + row) * 2];
    const unsigned long long o2 = part[((size_t)s * B_ + row) * 2 + 1];
    const unsigned long long n1 = o1 < b1 ? o1 : b1;
    const unsigned long long hm = o1 < b1 ? b1 : o1;
    const unsigned long long l2 = o2 < b2 ? o2 : b2;
    b1 = n1;
    b2 = hm < l2 ? hm : l2;
  }
  idx[row] = (int)(b1 & 0xffffffffull);
  const float s1 = ord2f((unsigned int)(b1 >> 32));
  const float s2 = ord2f((unsigned int)(b2 >> 32));
  if (s2 - s1 < TAU) {
    const int p = atomicAdd(counter, 1);
    flagged[p] = row;
  }
}

// ---------------- K5: exact fp32 recheck, 8 rows per emb sweep ----------------
__global__ __launch_bounds__(256)
void recheck_kernel(const int* __restrict__ counter, const int* __restrict__ flagged,
                    const float* __restrict__ e32, const float* __restrict__ emb,
                    const float* __restrict__ wnorm, int* __restrict__ idx) {
  __shared__ float er[8][256];
  __shared__ int frow[8];
  __shared__ unsigned long long red[4][8];
  const int t = threadIdx.x;
  const int lane = t & 63, wvv = t >> 6;
  const int n = *counter;
  const int G = (n + 7) / 8;
  for (int gi = blockIdx.x; gi < G; gi += gridDim.x) {
    const int nr = min(8, n - gi * 8);
    __syncthreads();
    if (t < 8) frow[t] = flagged[gi * 8 + (t < nr ? t : 0)];
    __syncthreads();
#pragma unroll
    for (int r = 0; r < 8; ++r) er[r][t] = e32[(size_t)frow[r] * L_ + t];
    __syncthreads();
    unsigned long long best[8];
#pragma unroll
    for (int r = 0; r < 8; ++r) best[r] = ~0ull;
    for (int cb = t * 2; cb < K_; cb += 512) {
      const float4* wr0 = (const float4*)(emb + (size_t)cb * L_);
      const float4* wr1 = (const float4*)(emb + (size_t)(cb + 1) * L_);
      float dot[8][2] = {};
#pragma unroll 8
      for (int l = 0; l < 64; ++l) {
        const float4 w0 = wr0[l];
        const float4 w1 = wr1[l];
#pragma unroll
        for (int r = 0; r < 8; ++r) {
          const float4 a = *(const float4*)&er[r][4 * l];
          dot[r][0] = fmaf(w0.x, a.x, dot[r][0]);
          dot[r][0] = fmaf(w0.y, a.y, dot[r][0]);
          dot[r][0] = fmaf(w0.z, a.z, dot[r][0]);
          dot[r][0] = fmaf(w0.w, a.w, dot[r][0]);
          dot[r][1] = fmaf(w1.x, a.x, dot[r][1]);
          dot[r][1] = fmaf(w1.y, a.y, dot[r][1]);
          dot[r][1] = fmaf(w1.z, a.z, dot[r][1]);
          dot[r][1] = fmaf(w1.w, a.w, dot[r][1]);
        }
      }
      const float wn0 = wnorm[cb], wn1 = wnorm[cb + 1];
#pragma unroll
      for (int r = 0; r < 8; ++r) {
        const float s0 = fmaf(-2.f, dot[r][0], wn0);
        const float s1 = fmaf(-2.f, dot[r][1], wn1);
        const unsigned long long k0 = ((unsigned long long)f2ord(s0) << 32) | (unsigned int)cb;
        const unsigned long long k1 = ((unsigned long long)f2ord(s1) << 32) | (unsigned int)(cb + 1);
        best[r] = k0 < best[r] ? k0 : best[r];
        best[r] = k1 < best[r] ? k1 : best[r];
      }
    }
#pragma unroll
    for (int off = 32; off > 0; off >>= 1)
#pragma unroll
      for (int r = 0; r < 8; ++r) {
        const unsigned long long o = __shfl_down(best[r], off, 64);
        best[r] = o < best[r] ? o : best[r];
      }
    if (lane == 0)
#pragma unroll
      for (int r = 0; r < 8; ++r) red[wvv][r] = best[r];
    __syncthreads();
    if (t < nr) {
      unsigned long long m = red[0][t];
#pragma unroll
      for (int q = 1; q < 4; ++q) m = red[q][t] < m ? red[q][t] : m;
      idx[frow[t]] = (int)(m & 0xffffffffull);
    }
  }
}

// ---------------- K6: decoder, split-bf16 MFMA ----------------
// grid 256 blocks x 256 threads; 64 batch rows per block.
__global__ __launch_bounds__(256)
void dec_mfma_kernel(const int* __restrict__ idx,
                     const unsigned short* __restrict__ emb_hi, const unsigned short* __restrict__ emb_lo,
                     const unsigned short* __restrict__ w1t_hi, const unsigned short* __restrict__ w1t_lo,
                     const unsigned short* __restrict__ w2t_hi, const unsigned short* __restrict__ w2t_lo,
                     const float* __restrict__ b1, const float* __restrict__ b2,
                     float* __restrict__ out) {
  __shared__ char stage[32768];
  __shared__ __align__(16) unsigned short g_hi[64][72];
  __shared__ __align__(16) unsigned short g_lo[64][72];
  __shared__ int idxs[64];
  const int t = threadIdx.x;
  const int lane = t & 63, wv = t >> 6;
  const long row0 = (long)blockIdx.x * 64;

  // staging swizzle constants (same scheme as distb; 16 rows x 64B per 1KB issue)
  const int lr = lane >> 2;
  const int sst = (lr + (lane >> 4)) & 3;
  const int qsrc = ((lane & 3) - sst) & 3;
  // fragment-read constants
  const int ln = lane & 15, quad = lane >> 4;
  const int sfr = (ln + (ln >> 2)) & 3;
  const int qp = (quad + sfr) & 3;

  if (t < 64) idxs[t] = idx[row0 + t];
  __syncthreads();

  // ---- phase 1: g = relu(zq @ w1 + b1); wave wv owns m-tile rows [16wv,16wv+16) ----
  floatx4 acc1[4];
#pragma unroll
  for (int nf = 0; nf < 4; ++nf) acc1[nf] = (floatx4){0.f, 0.f, 0.f, 0.f};

  for (int kc = 0; kc < 8; ++kc) {  // K=256, BK=32
    char* dst = stage + wv * 4096;
#pragma unroll
    for (int is = 0; is < 4; ++is) {
      const int row = is * 16 + lr;
      const char* src;
      if (wv == 0)      src = (const char*)(emb_hi + (size_t)idxs[row] * L_) + kc * 64 + qsrc * 16;
      else if (wv == 1) src = (const char*)(emb_lo + (size_t)idxs[row] * L_) + kc * 64 + qsrc * 16;
      else if (wv == 2) src = (const char*)(w1t_hi + (size_t)row * L_) + kc * 64 + qsrc * 16;
      else              src = (const char*)(w1t_lo + (size_t)row * L_) + kc * 64 + qsrc * 16;
      __builtin_amdgcn_global_load_lds((const AS1 void*)src, (AS3 void*)(dst + is * 1024), 16, 0, 0);
    }
    __syncthreads();
    const int arb = (16 * wv + ln) * 64 + qp * 16;
    const short8 ahi = *(const short8*)(stage + arb);
    const short8 alo = *(const short8*)(stage + 4096 + arb);
#pragma unroll
    for (int nf = 0; nf < 4; ++nf) {
      const int brb = (nf * 16 + ln) * 64 + qp * 16;
      const short8 bhi = *(const short8*)(stage + 8192 + brb);
      const short8 blo = *(const short8*)(stage + 12288 + brb);
      acc1[nf] = __builtin_amdgcn_mfma_f32_16x16x32_bf16(ahi, bhi, acc1[nf], 0, 0, 0);
      acc1[nf] = __builtin_amdgcn_mfma_f32_16x16x32_bf16(ahi, blo, acc1[nf], 0, 0, 0);
      acc1[nf] = __builtin_amdgcn_mfma_f32_16x16x32_bf16(alo, bhi, acc1[nf], 0, 0, 0);
    }
    __syncthreads();
  }
#pragma unroll
  for (int nf = 0; nf < 4; ++nf) {
    const int col = nf * 16 + ln;
    const float bias = b1[col];
#pragma unroll
    for (int rr = 0; rr < 4; ++rr) {
      const int row = 16 * wv + quad * 4 + rr;
      const float gv = fmaxf(acc1[nf][rr] + bias, 0.f);
      unsigned short hv, lv;
      bf16split(gv, &hv, &lv);
      g_hi[row][col] = hv;
      g_lo[row][col] = lv;
    }
  }
  __syncthreads();

  // ---- phase 2: out = g @ w2 + b2; loop 8 n-chunks of 128 cols ----
  for (int nc = 0; nc < 8; ++nc) {
    // stage w2t chunk [128 n][64 k] as 4 blocks of [128][32]: wv -> {hi k0, hi k1, lo k0, lo k1}
    char* dst = stage + wv * 8192;
    const unsigned short* base = (wv < 2) ? w2t_hi : w2t_lo;
    const int kh = wv & 1;
#pragma unroll
    for (int is = 0; is < 8; ++is) {
      const int row = is * 16 + lr;
      const char* src = (const char*)(base + (size_t)(nc * 128 + row) * H_) + kh * 64 + qsrc * 16;
      __builtin_amdgcn_global_load_lds((const AS1 void*)src, (AS3 void*)(dst + is * 1024), 16, 0, 0);
    }
    __syncthreads();
    floatx4 acc2[8];
#pragma unroll
    for (int nf = 0; nf < 8; ++nf) acc2[nf] = (floatx4){0.f, 0.f, 0.f, 0.f};
#pragma unroll
    for (int ks = 0; ks < 2; ++ks) {
      const int ab = (16 * wv + ln) * 144 + ks * 64 + quad * 16;
      const short8 ahi = *(const short8*)((const char*)g_hi + ab);
      const short8 alo = *(const short8*)((const char*)g_lo + ab);
#pragma unroll
      for (int nf = 0; nf < 8; ++nf) {
        const int brb = (nf * 16 + ln) * 64 + qp * 16;
        const short8 bhi = *(const short8*)(stage + ks * 8192 + brb);
        const short8 blo = *(const short8*)(stage + (2 + ks) * 8192 + brb);
        acc2[nf] = __builtin_amdgcn_mfma_f32_16x16x32_bf16(ahi, bhi, acc2[nf], 0, 0, 0);
        acc2[nf] = __builtin_amdgcn_mfma_f32_16x16x32_bf16(ahi, blo, acc2[nf], 0, 0, 0);
        acc2[nf] = __builtin_amdgcn_mfma_f32_16x16x32_bf16(alo, bhi, acc2[nf], 0, 0, 0);
      }
    }
    __syncthreads();
#pragma unroll
    for (int nf = 0; nf < 8; ++nf) {
      const int s = nc * 128 + nf * 16 + ln;
      const float bias = b2[s];
#pragma unroll
      for (int rr = 0; rr < 4; ++rr) {
        const long row = row0 + 16 * wv + quad * 4 + rr;
        out[row * S_ + s] = acc2[nf][rr] + bias;
      }
    }
  }
}

extern "C" void kernel_launch(void* const* d_in, const int* in_sizes, int n_in,
                              void* d_out, int out_size, void* d_ws, size_t ws_size,
                              hipStream_t stream) {
  (void)in_sizes; (void)n_in; (void)out_size; (void)ws_size;
  const float* x      = (const float*)d_in[0];
  const float* enc_w1 = (const float*)d_in[1];
  const float* enc_b1 = (const float*)d_in[2];
  const float* enc_w2 = (const float*)d_in[3];
  const float* enc_b2 = (const float*)d_in[4];
  const float* emb    = (const float*)d_in[5];
  const float* dec_w1 = (const float*)d_in[6];
  const float* dec_b1 = (const float*)d_in[7];
  const float* dec_w2 = (const float*)d_in[8];
  const float* dec_b2 = (const float*)d_in[9];
  float* out = (float*)d_out;

  char* p = (char*)d_ws;
  float* h    = (float*)p;          p += (size_t)B_ * H_ * 4;   // 4 MB
  float* e32  = (float*)p;          p += (size_t)B_ * L_ * 4;   // 16 MB
  unsigned short* e_hi = (unsigned short*)p;   p += (size_t)B_ * L_ * 2;  // 8 MB
  unsigned short* e_lo = (unsigned short*)p;   p += (size_t)B_ * L_ * 2;  // 8 MB
  unsigned short* emb_hi = (unsigned short*)p; p += (size_t)K_ * L_ * 2;  // 2 MB
  unsigned short* emb_lo = (unsigned short*)p; p += (size_t)K_ * L_ * 2;  // 2 MB
  unsigned short* w1t_hi = (unsigned short*)p; p += (size_t)H_ * L_ * 2;  // 32 KB
  unsigned short* w1t_lo = (unsigned short*)p; p += (size_t)H_ * L_ * 2;  // 32 KB
  unsigned short* w2t_hi = (unsigned short*)p; p += (size_t)S_ * H_ * 2;  // 128 KB
  unsigned short* w2t_lo = (unsigned short*)p; p += (size_t)S_ * H_ * 2;  // 128 KB
  float* wnrm = (float*)p;          p += (size_t)K_ * 4;        // 16 KB
  unsigned long long* part = (unsigned long long*)p; p += (size_t)16 * B_ * 2 * 8;  // 4 MB
  int* idx     = (int*)p;           p += (size_t)B_ * 4;        // 64 KB
  int* flagged = (int*)p;           p += (size_t)B_ * 4;        // 64 KB
  int* counter = (int*)p;           p += 256;

  hipMemsetAsync(counter, 0, 4, stream);
  wnorm_kernel<<<K_ / 4, 256, 0, stream>>>(emb, wnrm);
  cvt_emb_kernel<<<(K_ * L_) / 1024, 256, 0, stream>>>(emb, emb_hi, emb_lo);
  tsplit_kernel<<<dim3(1, 4), 256, 0, stream>>>(dec_w1, L_, H_, w1t_hi, w1t_lo);   // [256,64] -> [64][256]
  tsplit_kernel<<<dim3(16, 1), 256, 0, stream>>>(dec_w2, H_, S_, w2t_hi, w2t_lo);  // [64,1024] -> [1024][64]
  enc1_kernel<<<B_ / 64, 256, 0, stream>>>(x, enc_w1, enc_b1, h);
  enc2_kernel<<<B_ / 64, 256, 0, stream>>>(h, enc_w2, enc_b2, e32, e_hi, e_lo);
  distb_kernel<<<dim3(B_ / 128, 8), 256, 0, stream>>>(emb_hi, emb_lo, e_hi, e_lo, wnrm, part);
  finalize_kernel<<<B_ / 256, 256, 0, stream>>>(part, idx, flagged, counter);
  recheck_kernel<<<256, 256, 0, stream>>>(counter, flagged, e32, emb, wnrm, idx);
  dec_mfma_kernel<<<B_ / 64, 256, 0, stream>>>(idx, emb_hi, emb_lo, w1t_hi, w1t_lo,
                                               w2t_hi, w2t_lo, dec_b1, dec_b2, out);
}

// Round 4
// 356.029 us; speedup vs baseline: 1.4599x; 1.4599x over previous
//
#include <hip/hip_runtime.h>
#include <cstdint>

#define B_ 16384
#define S_ 1024
#define L_ 256
#define K_ 4096
#define H_ 64
#define TAU1 0.35f
#define TAU2 0.006f
#define SLOTCAP 8192

typedef __attribute__((ext_vector_type(8))) short short8;
typedef __attribute__((ext_vector_type(4))) float floatx4;

#define AS1 __attribute__((address_space(1)))
#define AS3 __attribute__((address_space(3)))

__device__ __forceinline__ unsigned int f2ord(float f) {
  unsigned int u = __float_as_uint(f);
  return (u & 0x80000000u) ? ~u : (u | 0x80000000u);
}
__device__ __forceinline__ float ord2f(unsigned int o) {
  unsigned int u = (o & 0x80000000u) ? (o ^ 0x80000000u) : ~o;
  return __uint_as_float(u);
}
// round-to-nearest-even fp32 -> bf16
__device__ __forceinline__ unsigned short bf16rne(float f, float* hif) {
  unsigned int u = __float_as_uint(f);
  unsigned int r = (u + 0x7fffu + ((u >> 16) & 1u)) >> 16;
  *hif = __uint_as_float(r << 16);
  return (unsigned short)r;
}
__device__ __forceinline__ void bf16split(float f, unsigned short* hi, unsigned short* lo) {
  float hif, d;
  *hi = bf16rne(f, &hif);
  *lo = bf16rne(f - hif, &d);
}

__device__ __forceinline__ void fma16(const float a[4], const float b[4], float acc[4][4]) {
#pragma unroll
  for (int ii = 0; ii < 4; ++ii)
#pragma unroll
    for (int jj = 0; jj < 4; ++jj)
      acc[ii][jj] = fmaf(a[ii], b[jj], acc[ii][jj]);
}

// ---------------- K0a: wnorm[c] = ||emb[c]||^2 ----------------
__global__ __launch_bounds__(256)
void wnorm_kernel(const float* __restrict__ emb, float* __restrict__ wnorm) {
  const int lane = threadIdx.x & 63, wv = threadIdx.x >> 6;
  const int c = blockIdx.x * 4 + wv;
  const float4 v = *(const float4*)(emb + (long)c * L_ + (lane << 2));
  float s = v.x * v.x + v.y * v.y + v.z * v.z + v.w * v.w;
#pragma unroll
  for (int off = 32; off > 0; off >>= 1) s += __shfl_down(s, off, 64);
  if (lane == 0) wnorm[c] = s;
}

// ---------------- K0b: emb -> bf16 hi/lo ----------------
__global__ __launch_bounds__(256)
void cvt_emb_kernel(const float* __restrict__ emb, unsigned short* __restrict__ hi,
                    unsigned short* __restrict__ lo) {
  const size_t i = ((size_t)blockIdx.x * 256 + threadIdx.x) * 4;
  const float4 v = *(const float4*)(emb + i);
  ushort4 hv, lv;
  bf16split(v.x, &hv.x, &lv.x);
  bf16split(v.y, &hv.y, &lv.y);
  bf16split(v.z, &hv.z, &lv.z);
  bf16split(v.w, &hv.w, &lv.w);
  *(ushort4*)(hi + i) = hv;
  *(ushort4*)(lo + i) = lv;
}

// ---------------- K0c: transpose+split: dst[c][r] = src[r][c] (hi/lo bf16) ----------------
__global__ __launch_bounds__(256)
void tsplit_kernel(const float* __restrict__ src, int srows, int scols,
                   unsigned short* __restrict__ hi, unsigned short* __restrict__ lo) {
  __shared__ float tile[64][68];
  const int t = threadIdx.x;
  const int r0 = blockIdx.y * 64, c0 = blockIdx.x * 64;
  const int a = t & 63, q = t >> 6;
#pragma unroll
  for (int i = 0; i < 4; ++i) {
    const int cq = q * 16 + i * 4;
    *(float4*)&tile[a][cq] = *(const float4*)(src + (size_t)(r0 + a) * scols + c0 + cq);
  }
  __syncthreads();
  const int rx = t & 15, cy = t >> 4;
#pragma unroll
  for (int i = 0; i < 4; ++i) {
    const int cl = i * 16 + cy;
    float4 w;
    w.x = tile[rx * 4 + 0][cl];
    w.y = tile[rx * 4 + 1][cl];
    w.z = tile[rx * 4 + 2][cl];
    w.w = tile[rx * 4 + 3][cl];
    ushort4 hv, lv;
    bf16split(w.x, &hv.x, &lv.x);
    bf16split(w.y, &hv.y, &lv.y);
    bf16split(w.z, &hv.z, &lv.z);
    bf16split(w.w, &hv.w, &lv.w);
    *(ushort4*)(hi + (size_t)(c0 + cl) * srows + r0 + rx * 4) = hv;
    *(ushort4*)(lo + (size_t)(c0 + cl) * srows + r0 + rx * 4) = lv;
  }
}

// ---------------- K1: h = relu(x @ w1 + b1), [k][r] LDS ----------------
__global__ __launch_bounds__(256)
void enc1_kernel(const float* __restrict__ x, const float* __restrict__ w1,
                 const float* __restrict__ b1, float* __restrict__ h) {
  __shared__ float xs[64][68];
  __shared__ float ws[64][64];
  const int t = threadIdx.x;
  const int tx = t & 15, ty = t >> 4;
  const long row0 = (long)blockIdx.x * 64;
  float acc[4][4] = {};
  for (int k0 = 0; k0 < S_; k0 += 64) {
#pragma unroll
    for (int i = 0; i < 4; ++i) {
      const int r = ty + 16 * i;
      const float4 v = *(const float4*)(x + (row0 + r) * S_ + k0 + (tx << 2));
      xs[4 * tx + 0][r] = v.x;
      xs[4 * tx + 1][r] = v.y;
      xs[4 * tx + 2][r] = v.z;
      xs[4 * tx + 3][r] = v.w;
    }
#pragma unroll
    for (int i = 0; i < 4; ++i) {
      const int g = (i << 8) + t;
      const int kk = g >> 4, c = (g & 15) << 2;
      *(float4*)&ws[kk][c] = *(const float4*)(w1 + (long)(k0 + kk) * H_ + c);
    }
    __syncthreads();
#pragma unroll 4
    for (int k = 0; k < 64; ++k) {
      float a[4], b[4];
      const float4 av = *(const float4*)&xs[k][ty << 2];
      a[0] = av.x; a[1] = av.y; a[2] = av.z; a[3] = av.w;
      const float4 bv = *(const float4*)&ws[k][tx << 2];
      b[0] = bv.x; b[1] = bv.y; b[2] = bv.z; b[3] = bv.w;
      fma16(a, b, acc);
    }
    __syncthreads();
  }
  const float4 bb = *(const float4*)(b1 + (tx << 2));
  const float bbv[4] = {bb.x, bb.y, bb.z, bb.w};
#pragma unroll
  for (int ii = 0; ii < 4; ++ii) {
    float4 o;
    o.x = fmaxf(acc[ii][0] + bbv[0], 0.f);
    o.y = fmaxf(acc[ii][1] + bbv[1], 0.f);
    o.z = fmaxf(acc[ii][2] + bbv[2], 0.f);
    o.w = fmaxf(acc[ii][3] + bbv[3], 0.f);
    *(float4*)(h + (row0 + (ty << 2) + ii) * H_ + (tx << 2)) = o;
  }
}

// ---------------- K2: e = h @ w2 + b2 (fp32 + bf16 hi/lo), [k][r] LDS ----------------
__global__ __launch_bounds__(256)
void enc2_kernel(const float* __restrict__ h, const float* __restrict__ w2,
                 const float* __restrict__ b2, float* __restrict__ e32,
                 unsigned short* __restrict__ e_hi, unsigned short* __restrict__ e_lo) {
  __shared__ float hs[64][68];
  __shared__ float ws[64][64];
  const int t = threadIdx.x;
  const int tx = t & 15, ty = t >> 4;
  const long row0 = (long)blockIdx.x * 64;
#pragma unroll
  for (int i = 0; i < 4; ++i) {
    const int r = ty + 16 * i;
    const float4 v = *(const float4*)(h + (row0 + r) * H_ + (tx << 2));
    hs[4 * tx + 0][r] = v.x;
    hs[4 * tx + 1][r] = v.y;
    hs[4 * tx + 2][r] = v.z;
    hs[4 * tx + 3][r] = v.w;
  }
  for (int c0 = 0; c0 < L_; c0 += 64) {
#pragma unroll
    for (int i = 0; i < 4; ++i) {
      const int g = (i << 8) + t;
      const int kk = g >> 4, c = (g & 15) << 2;
      *(float4*)&ws[kk][c] = *(const float4*)(w2 + (long)kk * L_ + c0 + c);
    }
    __syncthreads();
    float acc[4][4] = {};
#pragma unroll 4
    for (int k = 0; k < 64; ++k) {
      float a[4], b[4];
      const float4 av = *(const float4*)&hs[k][ty << 2];
      a[0] = av.x; a[1] = av.y; a[2] = av.z; a[3] = av.w;
      const float4 bv = *(const float4*)&ws[k][tx << 2];
      b[0] = bv.x; b[1] = bv.y; b[2] = bv.z; b[3] = bv.w;
      fma16(a, b, acc);
    }
    const float4 bb = *(const float4*)(b2 + c0 + (tx << 2));
#pragma unroll
    for (int ii = 0; ii < 4; ++ii) {
      const long row = row0 + (ty << 2) + ii;
      float4 o;
      o.x = acc[ii][0] + bb.x;
      o.y = acc[ii][1] + bb.y;
      o.z = acc[ii][2] + bb.z;
      o.w = acc[ii][3] + bb.w;
      *(float4*)(e32 + row * L_ + c0 + (tx << 2)) = o;
      ushort4 hv, lv;
      bf16split(o.x, &hv.x, &lv.x);
      bf16split(o.y, &hv.y, &lv.y);
      bf16split(o.z, &hv.z, &lv.z);
      bf16split(o.w, &hv.w, &lv.w);
      *(ushort4*)(e_hi + row * L_ + c0 + (tx << 2)) = hv;
      *(ushort4*)(e_lo + row * L_ + c0 + (tx << 2)) = lv;
    }
    __syncthreads();
  }
}

// ---------------- K3: pass-1 hi*hi distance + per-row top-2 ----------------
// grid (B_/128, 8). Block: 128 rows x (4 tiles of 128 codes). 1 MFMA term.
__global__ __launch_bounds__(256)
void dist_hi_kernel(const unsigned short* __restrict__ emb_hi,
                    const unsigned short* __restrict__ e_hi,
                    const float* __restrict__ wnorm, unsigned long long* __restrict__ part) {
  __shared__ char smem[16384];
  __shared__ float wnorm_s[128];
  const int t = threadIdx.x;
  const int lane = t & 63, wv = t >> 6;
  const int wm = wv >> 1, wn = wv & 1;
  const int n0 = blockIdx.x * 128;

  const int lr = lane >> 2;
  const int sst = (lr + (lane >> 4)) & 3;
  const int qsrc = ((lane & 3) - sst) & 3;
  const size_t lane_goff = (size_t)lr * (L_ * 2) + (size_t)qsrc * 16;

  const int ln = lane & 15, quad = lane >> 4;
  const int sfr = (ln + (ln >> 2)) & 3;
  const int qp = (quad + sfr) & 3;

  char* const sA = smem;
  char* const sB = smem + 8192;
  char* const myDst = (wv < 2 ? sA : sB) + (wv & 1) * 4096;
  const size_t rowHalfOff = (size_t)((wv & 1) * 64) * (L_ * 2);

  unsigned long long b1[4] = {~0ull, ~0ull, ~0ull, ~0ull};
  unsigned long long b2[4] = {~0ull, ~0ull, ~0ull, ~0ull};

  for (int mt = 0; mt < 4; ++mt) {
    const int m0 = (blockIdx.y * 4 + mt) * 128;
    const char* gbase = (wv < 2) ? (const char*)emb_hi + (size_t)m0 * (L_ * 2)
                                 : (const char*)e_hi + (size_t)n0 * (L_ * 2);
    gbase += rowHalfOff + lane_goff;

    floatx4 acc[4][4];
#pragma unroll
    for (int a = 0; a < 4; ++a)
#pragma unroll
      for (int b = 0; b < 4; ++b) acc[a][b] = (floatx4){0.f, 0.f, 0.f, 0.f};

    for (int kc = 0; kc < 8; ++kc) {
      const char* gsrc = gbase + kc * 64;
#pragma unroll
      for (int is = 0; is < 4; ++is) {
        __builtin_amdgcn_global_load_lds((const AS1 void*)(gsrc + (size_t)is * (16 * L_ * 2)),
                                         (AS3 void*)(myDst + is * 1024), 16, 0, 0);
      }
      __syncthreads();
      short8 ahi[4], bhi[4];
#pragma unroll
      for (int mf = 0; mf < 4; ++mf)
        ahi[mf] = *(const short8*)(sA + (wm * 64 + mf * 16 + ln) * 64 + qp * 16);
#pragma unroll
      for (int nf = 0; nf < 4; ++nf)
        bhi[nf] = *(const short8*)(sB + (wn * 64 + nf * 16 + ln) * 64 + qp * 16);
#pragma unroll
      for (int mf = 0; mf < 4; ++mf)
#pragma unroll
        for (int nf = 0; nf < 4; ++nf)
          acc[mf][nf] = __builtin_amdgcn_mfma_f32_16x16x32_bf16(ahi[mf], bhi[nf], acc[mf][nf], 0, 0, 0);
      __syncthreads();
    }
    if (t < 128) wnorm_s[t] = wnorm[m0 + t];
    __syncthreads();
#pragma unroll
    for (int nf = 0; nf < 4; ++nf) {
#pragma unroll
      for (int mf = 0; mf < 4; ++mf) {
#pragma unroll
        for (int rr = 0; rr < 4; ++rr) {
          const int ml = wm * 64 + mf * 16 + quad * 4 + rr;
          const float score = fmaf(-2.f, acc[mf][nf][rr], wnorm_s[ml]);
          const unsigned long long key =
              ((unsigned long long)f2ord(score) << 32) | (unsigned int)(m0 + ml);
          if (key < b1[nf]) { b2[nf] = b1[nf]; b1[nf] = key; }
          else if (key < b2[nf]) b2[nf] = key;
        }
      }
    }
    __syncthreads();
  }
#pragma unroll
  for (int d = 16; d <= 32; d <<= 1) {
#pragma unroll
    for (int nf = 0; nf < 4; ++nf) {
      const unsigned long long o1 = __shfl_xor(b1[nf], d, 64);
      const unsigned long long o2 = __shfl_xor(b2[nf], d, 64);
      const unsigned long long n1 = o1 < b1[nf] ? o1 : b1[nf];
      const unsigned long long hm = o1 < b1[nf] ? b1[nf] : o1;
      const unsigned long long l2 = o2 < b2[nf] ? o2 : b2[nf];
      b1[nf] = n1;
      b2[nf] = hm < l2 ? hm : l2;
    }
  }
  if (lane < 16) {
    const int slice = blockIdx.y * 2 + wm;
#pragma unroll
    for (int nf = 0; nf < 4; ++nf) {
      const int row = n0 + wn * 64 + nf * 16 + lane;
      const size_t slot = ((size_t)slice * B_ + row) * 2;
      part[slot] = b1[nf];
      part[slot + 1] = b2[nf];
    }
  }
}

// ---------------- K4: merge pass-1 partials, flag coarse-gap rows ----------------
__global__ __launch_bounds__(256)
void finalize1_kernel(const unsigned long long* __restrict__ part, int* __restrict__ idx,
                      int* __restrict__ flagged, int* __restrict__ counter) {
  const int row = blockIdx.x * 256 + threadIdx.x;
  unsigned long long b1 = ~0ull, b2 = ~0ull;
#pragma unroll
  for (int s = 0; s < 16; ++s) {
    const unsigned long long o1 = part[((size_t)s * B_ + row) * 2];
    const unsigned long long o2 = part[((size_t)s * B_ + row) * 2 + 1];
    const unsigned long long n1 = o1 < b1 ? o1 : b1;
    const unsigned long long hm = o1 < b1 ? b1 : o1;
    const unsigned long long l2 = o2 < b2 ? o2 : b2;
    b1 = n1;
    b2 = hm < l2 ? hm : l2;
  }
  idx[row] = (int)(b1 & 0xffffffffull);
  const float s1 = ord2f((unsigned int)(b1 >> 32));
  const float s2 = ord2f((unsigned int)(b2 >> 32));
  if (s2 - s1 < TAU1) {
    const int p = atomicAdd(counter, 1);
    flagged[p] = row;
  }
}

// ---------------- K5: pass-2 3-term split-bf16 on flagged rows ----------------
// grid (16 rowgroup-stride, 16 slices of 256 codes); gathered e rows.
__global__ __launch_bounds__(256)
void dist3_kernel(const unsigned short* __restrict__ emb_hi, const unsigned short* __restrict__ emb_lo,
                  const unsigned short* __restrict__ e_hi, const unsigned short* __restrict__ e_lo,
                  const float* __restrict__ wnorm, const int* __restrict__ counter,
                  const int* __restrict__ flagged, unsigned long long* __restrict__ part2) {
  __shared__ char smem[4 * 8192];
  __shared__ float wnorm_s[128];
  __shared__ int frow_s[128];
  const int t = threadIdx.x;
  const int lane = t & 63, wv = t >> 6;
  const int wm = wv >> 1, wn = wv & 1;
  const int slice = blockIdx.y;
  const int n = min(*counter, SLOTCAP);

  const int lr = lane >> 2;
  const int sst = (lr + (lane >> 4)) & 3;
  const int qsrc = ((lane & 3) - sst) & 3;
  const int ln = lane & 15, quad = lane >> 4;
  const int sfr = (ln + (ln >> 2)) & 3;
  const int qp = (quad + sfr) & 3;

  char* const sAhi = smem;
  char* const sAlo = smem + 8192;
  char* const sBhi = smem + 16384;
  char* const sBlo = smem + 24576;
  char* const myTile = smem + wv * 8192;

  for (int gi = blockIdx.x; gi * 128 < n; gi += 16) {
    const int s0 = gi * 128;
    __syncthreads();
    if (t < 128) frow_s[t] = flagged[min(s0 + t, n - 1)];
    __syncthreads();
    unsigned long long b1[4] = {~0ull, ~0ull, ~0ull, ~0ull};
    unsigned long long b2[4] = {~0ull, ~0ull, ~0ull, ~0ull};

    for (int mt = 0; mt < 2; ++mt) {
      const int m0 = slice * 256 + mt * 128;
      floatx4 acc[4][4];
#pragma unroll
      for (int a = 0; a < 4; ++a)
#pragma unroll
        for (int b = 0; b < 4; ++b) acc[a][b] = (floatx4){0.f, 0.f, 0.f, 0.f};

      for (int kc = 0; kc < 8; ++kc) {
#pragma unroll
        for (int is = 0; is < 8; ++is) {
          const int row = is * 16 + lr;
          const char* src;
          if (wv == 0)      src = (const char*)(emb_hi + (size_t)(m0 + row) * L_);
          else if (wv == 1) src = (const char*)(emb_lo + (size_t)(m0 + row) * L_);
          else if (wv == 2) src = (const char*)(e_hi + (size_t)frow_s[row] * L_);
          else              src = (const char*)(e_lo + (size_t)frow_s[row] * L_);
          src += kc * 64 + qsrc * 16;
          __builtin_amdgcn_global_load_lds((const AS1 void*)src,
                                           (AS3 void*)(myTile + is * 1024), 16, 0, 0);
        }
        __syncthreads();
        short8 ahi[4], alo[4], bhi[4], blo[4];
#pragma unroll
        for (int mf = 0; mf < 4; ++mf) {
          const int rb = (mf * 16 + wm * 64 + ln) * 64 + qp * 16;
          ahi[mf] = *(const short8*)(sAhi + rb);
          alo[mf] = *(const short8*)(sAlo + rb);
        }
#pragma unroll
        for (int nf = 0; nf < 4; ++nf) {
          const int rb = (nf * 16 + wn * 64 + ln) * 64 + qp * 16;
          bhi[nf] = *(const short8*)(sBhi + rb);
          blo[nf] = *(const short8*)(sBlo + rb);
        }
#pragma unroll
        for (int mf = 0; mf < 4; ++mf)
#pragma unroll
          for (int nf = 0; nf < 4; ++nf) {
            acc[mf][nf] = __builtin_amdgcn_mfma_f32_16x16x32_bf16(ahi[mf], bhi[nf], acc[mf][nf], 0, 0, 0);
            acc[mf][nf] = __builtin_amdgcn_mfma_f32_16x16x32_bf16(ahi[mf], blo[nf], acc[mf][nf], 0, 0, 0);
            acc[mf][nf] = __builtin_amdgcn_mfma_f32_16x16x32_bf16(alo[mf], bhi[nf], acc[mf][nf], 0, 0, 0);
          }
        __syncthreads();
      }
      if (t < 128) wnorm_s[t] = wnorm[m0 + t];
      __syncthreads();
#pragma unroll
      for (int nf = 0; nf < 4; ++nf) {
#pragma unroll
        for (int mf = 0; mf < 4; ++mf) {
#pragma unroll
          for (int rr = 0; rr < 4; ++rr) {
            const int ml = wm * 64 + mf * 16 + quad * 4 + rr;
            const float score = fmaf(-2.f, acc[mf][nf][rr], wnorm_s[ml]);
            const unsigned long long key =
                ((unsigned long long)f2ord(score) << 32) | (unsigned int)(m0 + ml);
            if (key < b1[nf]) { b2[nf] = b1[nf]; b1[nf] = key; }
            else if (key < b2[nf]) b2[nf] = key;
          }
        }
      }
      __syncthreads();
    }
#pragma unroll
    for (int d = 16; d <= 32; d <<= 1) {
#pragma unroll
      for (int nf = 0; nf < 4; ++nf) {
        const unsigned long long o1 = __shfl_xor(b1[nf], d, 64);
        const unsigned long long o2 = __shfl_xor(b2[nf], d, 64);
        const unsigned long long n1 = o1 < b1[nf] ? o1 : b1[nf];
        const unsigned long long hm = o1 < b1[nf] ? b1[nf] : o1;
        const unsigned long long l2 = o2 < b2[nf] ? o2 : b2[nf];
        b1[nf] = n1;
        b2[nf] = hm < l2 ? hm : l2;
      }
    }
    if (lane < 16) {
      const int sub = slice * 2 + wm;   // 32 sub-slices
#pragma unroll
      for (int nf = 0; nf < 4; ++nf) {
        const int slot = s0 + wn * 64 + nf * 16 + lane;
        if (slot < n) {
          const size_t o = ((size_t)sub * SLOTCAP + slot) * 2;
          part2[o] = b1[nf];
          part2[o + 1] = b2[nf];
        }
      }
    }
  }
}

// ---------------- K6: merge pass-2 partials, flag fine-gap rows ----------------
__global__ __launch_bounds__(256)
void finalize2_kernel(const unsigned long long* __restrict__ part2, const int* __restrict__ counter,
                      const int* __restrict__ flagged, int* __restrict__ idx,
                      int* __restrict__ flagged2, int* __restrict__ counter2) {
  const int n = min(*counter, SLOTCAP);
  const int s = blockIdx.x * 256 + threadIdx.x;
  if (s >= n) return;
  unsigned long long b1 = ~0ull, b2 = ~0ull;
#pragma unroll
  for (int sub = 0; sub < 32; ++sub) {
    const size_t o = ((size_t)sub * SLOTCAP + s) * 2;
    const unsigned long long o1 = part2[o];
    const unsigned long long o2 = part2[o + 1];
    const unsigned long long n1 = o1 < b1 ? o1 : b1;
    const unsigned long long hm = o1 < b1 ? b1 : o1;
    const unsigned long long l2 = o2 < b2 ? o2 : b2;
    b1 = n1;
    b2 = hm < l2 ? hm : l2;
  }
  const int row = flagged[s];
  idx[row] = (int)(b1 & 0xffffffffull);
  const float s1 = ord2f((unsigned int)(b1 >> 32));
  const float s2 = ord2f((unsigned int)(b2 >> 32));
  if (s2 - s1 < TAU2) {
    const int p = atomicAdd(counter2, 1);
    flagged2[p] = row;
  }
}

// ---------------- K7: exact fp32 recheck (parallel over code chunks) ----------------
// grid (16 code-chunks, 16 row-slots)
__global__ __launch_bounds__(256)
void recheck_kernel(const int* __restrict__ counter2, const int* __restrict__ flagged2,
                    const float* __restrict__ e32, const float* __restrict__ emb,
                    const float* __restrict__ wnorm, unsigned long long* __restrict__ keys2) {
  __shared__ float er[L_];
  const int t = threadIdx.x;
  const int lane = t & 63;
  const int n2 = *counter2;
  for (int i = blockIdx.y; i < n2; i += 16) {
    const int row = flagged2[i];
    __syncthreads();
    er[t] = e32[(size_t)row * L_ + t];
    __syncthreads();
    const int c = blockIdx.x * 256 + t;
    const float4* wr = (const float4*)(emb + (size_t)c * L_);
    float dot = 0.f;
#pragma unroll 16
    for (int l = 0; l < 64; ++l) {
      const float4 w = wr[l];
      dot = fmaf(w.x, er[4 * l + 0], dot);
      dot = fmaf(w.y, er[4 * l + 1], dot);
      dot = fmaf(w.z, er[4 * l + 2], dot);
      dot = fmaf(w.w, er[4 * l + 3], dot);
    }
    const float score = fmaf(-2.f, dot, wnorm[c]);
    unsigned long long key = ((unsigned long long)f2ord(score) << 32) | (unsigned int)c;
#pragma unroll
    for (int off = 32; off > 0; off >>= 1) {
      const unsigned long long o = __shfl_down(key, off, 64);
      key = o < key ? o : key;
    }
    if (lane == 0) atomicMin(&keys2[row], key);
  }
}

// ---------------- K8: write rechecked indices ----------------
__global__ __launch_bounds__(256)
void extract_kernel(const int* __restrict__ counter2, const int* __restrict__ flagged2,
                    const unsigned long long* __restrict__ keys2, int* __restrict__ idx) {
  const int n2 = *counter2;
  for (int i = threadIdx.x; i < n2; i += 256) {
    const int r = flagged2[i];
    idx[r] = (int)(keys2[r] & 0xffffffffull);
  }
}

// ---------------- K9: decoder, split-bf16 MFMA ----------------
__global__ __launch_bounds__(256)
void dec_mfma_kernel(const int* __restrict__ idx,
                     const unsigned short* __restrict__ emb_hi, const unsigned short* __restrict__ emb_lo,
                     const unsigned short* __restrict__ w1t_hi, const unsigned short* __restrict__ w1t_lo,
                     const unsigned short* __restrict__ w2t_hi, const unsigned short* __restrict__ w2t_lo,
                     const float* __restrict__ b1, const float* __restrict__ b2,
                     float* __restrict__ out) {
  __shared__ char stage[32768];
  __shared__ __align__(16) unsigned short g_hi[64][72];
  __shared__ __align__(16) unsigned short g_lo[64][72];
  __shared__ int idxs[64];
  const int t = threadIdx.x;
  const int lane = t & 63, wv = t >> 6;
  const long row0 = (long)blockIdx.x * 64;

  const int lr = lane >> 2;
  const int sst = (lr + (lane >> 4)) & 3;
  const int qsrc = ((lane & 3) - sst) & 3;
  const int ln = lane & 15, quad = lane >> 4;
  const int sfr = (ln + (ln >> 2)) & 3;
  const int qp = (quad + sfr) & 3;

  if (t < 64) idxs[t] = idx[row0 + t];
  __syncthreads();

  floatx4 acc1[4];
#pragma unroll
  for (int nf = 0; nf < 4; ++nf) acc1[nf] = (floatx4){0.f, 0.f, 0.f, 0.f};

  for (int kc = 0; kc < 8; ++kc) {
    char* dst = stage + wv * 4096;
#pragma unroll
    for (int is = 0; is < 4; ++is) {
      const int row = is * 16 + lr;
      const char* src;
      if (wv == 0)      src = (const char*)(emb_hi + (size_t)idxs[row] * L_) + kc * 64 + qsrc * 16;
      else if (wv == 1) src = (const char*)(emb_lo + (size_t)idxs[row] * L_) + kc * 64 + qsrc * 16;
      else if (wv == 2) src = (const char*)(w1t_hi + (size_t)row * L_) + kc * 64 + qsrc * 16;
      else              src = (const char*)(w1t_lo + (size_t)row * L_) + kc * 64 + qsrc * 16;
      __builtin_amdgcn_global_load_lds((const AS1 void*)src, (AS3 void*)(dst + is * 1024), 16, 0, 0);
    }
    __syncthreads();
    const int arb = (16 * wv + ln) * 64 + qp * 16;
    const short8 ahi = *(const short8*)(stage + arb);
    const short8 alo = *(const short8*)(stage + 4096 + arb);
#pragma unroll
    for (int nf = 0; nf < 4; ++nf) {
      const int brb = (nf * 16 + ln) * 64 + qp * 16;
      const short8 bhi = *(const short8*)(stage + 8192 + brb);
      const short8 blo = *(const short8*)(stage + 12288 + brb);
      acc1[nf] = __builtin_amdgcn_mfma_f32_16x16x32_bf16(ahi, bhi, acc1[nf], 0, 0, 0);
      acc1[nf] = __builtin_amdgcn_mfma_f32_16x16x32_bf16(ahi, blo, acc1[nf], 0, 0, 0);
      acc1[nf] = __builtin_amdgcn_mfma_f32_16x16x32_bf16(alo, bhi, acc1[nf], 0, 0, 0);
    }
    __syncthreads();
  }
#pragma unroll
  for (int nf = 0; nf < 4; ++nf) {
    const int col = nf * 16 + ln;
    const float bias = b1[col];
#pragma unroll
    for (int rr = 0; rr < 4; ++rr) {
      const int row = 16 * wv + quad * 4 + rr;
      const float gv = fmaxf(acc1[nf][rr] + bias, 0.f);
      unsigned short hv, lv;
      bf16split(gv, &hv, &lv);
      g_hi[row][col] = hv;
      g_lo[row][col] = lv;
    }
  }
  __syncthreads();

  for (int nc = 0; nc < 8; ++nc) {
    char* dst = stage + wv * 8192;
    const unsigned short* base = (wv < 2) ? w2t_hi : w2t_lo;
    const int kh = wv & 1;
#pragma unroll
    for (int is = 0; is < 8; ++is) {
      const int row = is * 16 + lr;
      const char* src = (const char*)(base + (size_t)(nc * 128 + row) * H_) + kh * 64 + qsrc * 16;
      __builtin_amdgcn_global_load_lds((const AS1 void*)src, (AS3 void*)(dst + is * 1024), 16, 0, 0);
    }
    __syncthreads();
    floatx4 acc2[8];
#pragma unroll
    for (int nf = 0; nf < 8; ++nf) acc2[nf] = (floatx4){0.f, 0.f, 0.f, 0.f};
#pragma unroll
    for (int ks = 0; ks < 2; ++ks) {
      const int ab = (16 * wv + ln) * 144 + ks * 64 + quad * 16;
      const short8 ahi = *(const short8*)((const char*)g_hi + ab);
      const short8 alo = *(const short8*)((const char*)g_lo + ab);
#pragma unroll
      for (int nf = 0; nf < 8; ++nf) {
        const int brb = (nf * 16 + ln) * 64 + qp * 16;
        const short8 bhi = *(const short8*)(stage + ks * 8192 + brb);
        const short8 blo = *(const short8*)(stage + (2 + ks) * 8192 + brb);
        acc2[nf] = __builtin_amdgcn_mfma_f32_16x16x32_bf16(ahi, bhi, acc2[nf], 0, 0, 0);
        acc2[nf] = __builtin_amdgcn_mfma_f32_16x16x32_bf16(ahi, blo, acc2[nf], 0, 0, 0);
        acc2[nf] = __builtin_amdgcn_mfma_f32_16x16x32_bf16(alo, bhi, acc2[nf], 0, 0, 0);
      }
    }
    __syncthreads();
#pragma unroll
    for (int nf = 0; nf < 8; ++nf) {
      const int s = nc * 128 + nf * 16 + ln;
      const float bias = b2[s];
#pragma unroll
      for (int rr = 0; rr < 4; ++rr) {
        const long row = row0 + 16 * wv + quad * 4 + rr;
        out[row * S_ + s] = acc2[nf][rr] + bias;
      }
    }
  }
}

extern "C" void kernel_launch(void* const* d_in, const int* in_sizes, int n_in,
                              void* d_out, int out_size, void* d_ws, size_t ws_size,
                              hipStream_t stream) {
  (void)in_sizes; (void)n_in; (void)out_size; (void)ws_size;
  const float* x      = (const float*)d_in[0];
  const float* enc_w1 = (const float*)d_in[1];
  const float* enc_b1 = (const float*)d_in[2];
  const float* enc_w2 = (const float*)d_in[3];
  const float* enc_b2 = (const float*)d_in[4];
  const float* emb    = (const float*)d_in[5];
  const float* dec_w1 = (const float*)d_in[6];
  const float* dec_b1 = (const float*)d_in[7];
  const float* dec_w2 = (const float*)d_in[8];
  const float* dec_b2 = (const float*)d_in[9];
  float* out = (float*)d_out;

  char* p = (char*)d_ws;
  float* h    = (float*)p;          p += (size_t)B_ * H_ * 4;   // 4 MB
  float* e32  = (float*)p;          p += (size_t)B_ * L_ * 4;   // 16 MB
  unsigned short* e_hi = (unsigned short*)p;   p += (size_t)B_ * L_ * 2;  // 8 MB
  unsigned short* e_lo = (unsigned short*)p;   p += (size_t)B_ * L_ * 2;  // 8 MB
  unsigned short* emb_hi = (unsigned short*)p; p += (size_t)K_ * L_ * 2;  // 2 MB
  unsigned short* emb_lo = (unsigned short*)p; p += (size_t)K_ * L_ * 2;  // 2 MB
  unsigned short* w1t_hi = (unsigned short*)p; p += (size_t)H_ * L_ * 2;  // 32 KB
  unsigned short* w1t_lo = (unsigned short*)p; p += (size_t)H_ * L_ * 2;  // 32 KB
  unsigned short* w2t_hi = (unsigned short*)p; p += (size_t)S_ * H_ * 2;  // 128 KB
  unsigned short* w2t_lo = (unsigned short*)p; p += (size_t)S_ * H_ * 2;  // 128 KB
  float* wnrm = (float*)p;          p += (size_t)K_ * 4;        // 16 KB
  unsigned long long* part  = (unsigned long long*)p; p += (size_t)16 * B_ * 2 * 8;      // 4 MB
  unsigned long long* part2 = (unsigned long long*)p; p += (size_t)32 * SLOTCAP * 2 * 8; // 4 MB
  unsigned long long* keys2 = (unsigned long long*)p; p += (size_t)B_ * 8;               // 128 KB
  int* idx      = (int*)p;          p += (size_t)B_ * 4;        // 64 KB
  int* flagged  = (int*)p;          p += (size_t)B_ * 4;        // 64 KB
  int* flagged2 = (int*)p;          p += (size_t)B_ * 4;        // 64 KB
  int* counters = (int*)p;          p += 256;                   // [0]=n flagged, [1]=n2

  hipMemsetAsync(counters, 0, 8, stream);
  hipMemsetAsync(keys2, 0xFF, (size_t)B_ * 8, stream);
  wnorm_kernel<<<K_ / 4, 256, 0, stream>>>(emb, wnrm);
  cvt_emb_kernel<<<(K_ * L_) / 1024, 256, 0, stream>>>(emb, emb_hi, emb_lo);
  tsplit_kernel<<<dim3(1, 4), 256, 0, stream>>>(dec_w1, L_, H_, w1t_hi, w1t_lo);
  tsplit_kernel<<<dim3(16, 1), 256, 0, stream>>>(dec_w2, H_, S_, w2t_hi, w2t_lo);
  enc1_kernel<<<B_ / 64, 256, 0, stream>>>(x, enc_w1, enc_b1, h);
  enc2_kernel<<<B_ / 64, 256, 0, stream>>>(h, enc_w2, enc_b2, e32, e_hi, e_lo);
  dist_hi_kernel<<<dim3(B_ / 128, 8), 256, 0, stream>>>(emb_hi, e_hi, wnrm, part);
  finalize1_kernel<<<B_ / 256, 256, 0, stream>>>(part, idx, flagged, counters);
  dist3_kernel<<<dim3(16, 16), 256, 0, stream>>>(emb_hi, emb_lo, e_hi, e_lo, wnrm,
                                                 counters, flagged, part2);
  finalize2_kernel<<<SLOTCAP / 256, 256, 0, stream>>>(part2, counters, flagged, idx,
                                                      flagged2, counters + 1);
  recheck_kernel<<<dim3(16, 16), 256, 0, stream>>>(counters + 1, flagged2, e32, emb, wnrm, keys2);
  extract_kernel<<<1, 256, 0, stream>>>(counters + 1, flagged2, keys2, idx);
  dec_mfma_kernel<<<B_ / 64, 256, 0, stream>>>(idx, emb_hi, emb_lo, w1t_hi, w1t_lo,
                                               w2t_hi, w2t_lo, dec_b1, dec_b2, out);
}